// Round 1
// baseline (164.647 us; speedup 1.0000x reference)
//
#include <hip/hip_runtime.h>
#include <math.h>

// ---------------------------------------------------------------------------
// Strict2_5DLoss — 3-level triangle detection loss, forward only.
//
// Structure exploited:
//  * pos_mask region for each (b,g) triangle lies inside its bbox + ETA
//    -> per-(level,b,g) workgroup scans only the bbox (~hundreds of cells).
//  * obj BCE = sum softplus(obj) over ALL pixels (dense reduction)
//              + per-distinct-selected-pixel correction
//                (POS_W*softplus(-x) - softplus(x)); dedup via atomicOr bitmask.
//  * top_k(K=64) of -masked == K lexicographically smallest (dist, idx);
//    tie-break by smaller index matches lax.top_k.
//  * invalid (vf=0) top-k slots contribute nothing -> skipped entirely.
// ---------------------------------------------------------------------------

#define K_SEL 64
#define CAP   4096          // LDS candidate capacity (bbox cells are ~<=2.5K)
#define NBLK_SEL 768        // 3 levels * 8 batch * 32 gt
#define NBLK_RED 256
#define TOTAL_PIX 688128.0f // 8*(65536+16384+4096)

__device__ __forceinline__ float softplus_f(float x) {
    // jax.nn.softplus: max(x,0) + log1p(exp(-|x|))
    return fmaxf(x, 0.0f) + log1pf(expf(-fabsf(x)));
}

__device__ __forceinline__ float seg_dist(float px, float py,
                                          float x1, float y1, float x2, float y2) {
    float vx = x2 - x1, vy = y2 - y1;
    float wx = px - x1, wy = py - y1;
    float t = (wx * vx + wy * vy) / (vx * vx + vy * vy + 1e-9f);
    t = fminf(fmaxf(t, 0.0f), 1.0f);
    float dx = px - (x1 + t * vx), dy = py - (y1 + t * vy);
    return sqrtf(dx * dx + dy * dy + 1e-12f);
}

__device__ __forceinline__ bool tri_mask_dist(float px, float py,
    float Ax, float Ay, float Bx, float By, float Cx, float Cy, float* dout) {
    float d1 = (px - Bx) * (Ay - By) - (Ax - Bx) * (py - By);
    float d2 = (px - Cx) * (By - Cy) - (Bx - Cx) * (py - Cy);
    float d3 = (px - Ax) * (Cy - Ay) - (Cx - Ax) * (py - Ay);
    bool has_neg = (d1 < 0.f) || (d2 < 0.f) || (d3 < 0.f);
    bool has_pos = (d1 > 0.f) || (d2 > 0.f) || (d3 > 0.f);
    bool inside = !(has_neg && has_pos);
    float dist = fminf(seg_dist(px, py, Ax, Ay, Bx, By),
                 fminf(seg_dist(px, py, Bx, By, Cx, Cy),
                       seg_dist(px, py, Cx, Cy, Ax, Ay)));
    *dout = dist;
    return inside || (dist <= 3.0f);
}

// facc: [0]=reg_s [1]=cls_s [2]=obj_base [3]=obj_corr ; uacc: [0]=pos [1]=pos_now
__global__ __launch_bounds__(256)
void s25d_mega(const float* __restrict__ reg0, const float* __restrict__ obj0, const float* __restrict__ cls0,
               const float* __restrict__ reg1, const float* __restrict__ obj1, const float* __restrict__ cls1,
               const float* __restrict__ reg2, const float* __restrict__ obj2, const float* __restrict__ cls2,
               const float* __restrict__ gt,
               float* facc, unsigned* uacc, unsigned* flags) {
    const int bid = blockIdx.x;
    const int tid = threadIdx.x;

    if (bid < NBLK_SEL) {
        // -------------------- per-(level, b, g) selection block --------------------
        const int level = bid >> 8;
        const int pair  = bid & 255;
        const int b = pair >> 5, g = pair & 31;

        const float* regp; const float* objp; const float* clsp;
        int Ws, log2Ws, flagBase; float stride;
        if (level == 0)      { regp = reg0; objp = obj0; clsp = cls0; Ws = 256; log2Ws = 8; stride =  8.f; flagBase = 0; }
        else if (level == 1) { regp = reg1; objp = obj1; clsp = cls1; Ws = 128; log2Ws = 7; stride = 16.f; flagBase = 16384; }
        else                 { regp = reg2; objp = obj2; clsp = cls2; Ws =  64; log2Ws = 6; stride = 32.f; flagBase = 20480; }
        const int HW = Ws * Ws;

        const float* tri = gt + (size_t)((b * 32 + g) * 3) * 2;
        const float Ax = tri[0], Ay = tri[1], Bx = tri[2], By = tri[3], Cx = tri[4], Cy = tri[5];

        __shared__ float sd[CAP];
        __shared__ int   si[CAP];
        __shared__ int   scnt;
        __shared__ int   sovf;
        if (tid == 0) { scnt = 0; sovf = 0; }
        __syncthreads();

        // conservative bbox (+ETA, then an extra-cell slack via floor/ceil)
        float minx = fminf(Ax, fminf(Bx, Cx)) - 3.0f;
        float maxx = fmaxf(Ax, fmaxf(Bx, Cx)) + 3.0f;
        float miny = fminf(Ay, fminf(By, Cy)) - 3.0f;
        float maxy = fmaxf(Ay, fmaxf(By, Cy)) + 3.0f;
        int ix_lo = max(0,      (int)floorf(minx / stride - 0.5f));
        int ix_hi = min(Ws - 1, (int)ceilf (maxx / stride - 0.5f));
        int iy_lo = max(0,      (int)floorf(miny / stride - 0.5f));
        int iy_hi = min(Ws - 1, (int)ceilf (maxy / stride - 0.5f));
        int nx = ix_hi - ix_lo + 1, ny = iy_hi - iy_lo + 1;
        int ncells = (nx > 0 && ny > 0) ? nx * ny : 0;

        for (int c = tid; c < ncells; c += 256) {
            int ix = ix_lo + (c % nx);
            int iy = iy_lo + (c / nx);
            float px = (ix + 0.5f) * stride, py = (iy + 0.5f) * stride;
            float d;
            if (tri_mask_dist(px, py, Ax, Ay, Bx, By, Cx, Cy, &d)) {
                int slot = atomicAdd(&scnt, 1);
                if (slot < CAP) { sd[slot] = d; si[slot] = (iy << log2Ws) | ix; }
                else sovf = 1;
            }
        }
        __syncthreads();
        const int  cnt = scnt;
        const bool ovf = (sovf != 0);

        __shared__ int   sel_idx[K_SEL];
        __shared__ float red_d[256];
        __shared__ int   red_i[256];
        int sel_cnt;

        if (!ovf && cnt <= K_SEL) {
            sel_cnt = cnt;
            if (tid < cnt) sel_idx[tid] = si[tid];   // set semantics, order irrelevant
        } else {
            sel_cnt = K_SEL;
            float last_d = -1.0f; int last_i = -1;   // dist >= 1e-6 > -1 always
            for (int k = 0; k < K_SEL; ++k) {
                float md = INFINITY; int mi = 0x7fffffff;
                if (!ovf) {
                    for (int c = tid; c < cnt; c += 256) {
                        float d = sd[c]; int i = si[c];
                        bool after_last = (d > last_d) || (d == last_d && i > last_i);
                        if (after_last && (d < md || (d == md && i < mi))) { md = d; mi = i; }
                    }
                } else {
                    // slow path (candidates overflowed LDS): recompute over bbox
                    for (int c = tid; c < ncells; c += 256) {
                        int ix = ix_lo + (c % nx);
                        int iy = iy_lo + (c / nx);
                        float px = (ix + 0.5f) * stride, py = (iy + 0.5f) * stride;
                        float d;
                        if (tri_mask_dist(px, py, Ax, Ay, Bx, By, Cx, Cy, &d)) {
                            int i = (iy << log2Ws) | ix;
                            bool after_last = (d > last_d) || (d == last_d && i > last_i);
                            if (after_last && (d < md || (d == md && i < mi))) { md = d; mi = i; }
                        }
                    }
                }
                red_d[tid] = md; red_i[tid] = mi;
                __syncthreads();
                for (int s = 128; s > 0; s >>= 1) {
                    if (tid < s) {
                        float d2 = red_d[tid + s]; int i2 = red_i[tid + s];
                        if (d2 < red_d[tid] || (d2 == red_d[tid] && i2 < red_i[tid])) {
                            red_d[tid] = d2; red_i[tid] = i2;
                        }
                    }
                    __syncthreads();
                }
                if (tid == 0) sel_idx[k] = red_i[0];
                last_d = red_d[0]; last_i = red_i[0];
                __syncthreads();   // protect red_* before next iteration writes
            }
        }
        __syncthreads();

        // -------------------- process selected (all vf==1) --------------------
        float my_reg = 0.f, my_cls = 0.f, my_corr = 0.f; int my_first = 0;
        if (tid < sel_cnt) {
            int hw = sel_idx[tid];
            int ix = hw & (Ws - 1), iy = hw >> log2Ws;
            float ax = (ix + 0.5f) * stride, ay = (iy + 0.5f) * stride;
            int pix = b * HW + hw;

            // distinct-pixel dedup (per level, per batch) for obj_t / pos_now
            int word = flagBase + (pix >> 5);
            unsigned bit = 1u << (pix & 31);
            unsigned old = atomicOr(&flags[word], bit);
            if (!(old & bit)) {
                my_first = 1;
                float x = objp[pix];
                my_corr = 1.2f * softplus_f(-x) - softplus_f(x);
            }
            my_cls = softplus_f(-clsp[pix]);

            float inv = 1.0f / stride;
            float p[6];
#pragma unroll
            for (int ch = 0; ch < 6; ++ch) {
                float v = regp[(size_t)(b * 6 + ch) * HW + hw];
                p[ch] = fminf(fmaxf(v, -64.f), 64.f);
            }
            float g0x = (Ax - ax) * inv, g0y = (Ay - ay) * inv;
            float g1x = (Bx - ax) * inv, g1y = (By - ay) * inv;
            float g2x = (Cx - ax) * inv, g2y = (Cy - ay) * inv;
            float p0 = (p[0] - g0x) * (p[0] - g0x) + (p[1] - g0y) * (p[1] - g0y);
            float d00 = sqrtf((p[2] - g1x) * (p[2] - g1x) + (p[3] - g1y) * (p[3] - g1y));
            float d01 = sqrtf((p[2] - g2x) * (p[2] - g2x) + (p[3] - g2y) * (p[3] - g2y));
            float d10 = sqrtf((p[4] - g1x) * (p[4] - g1x) + (p[5] - g1y) * (p[5] - g1y));
            float d11 = sqrtf((p[4] - g2x) * (p[4] - g2x) + (p[5] - g2y) * (p[5] - g2y));
            float cd = fminf(d00, d01) + fminf(d10, d11) + fminf(d00, d10) + fminf(d01, d11);
            my_reg = p0 + cd;   // L_P0 = L_CD = 1
        }

        __shared__ float rsum[K_SEL], csum[K_SEL], osum[K_SEL];
        __shared__ int   fsum[K_SEL];
        if (tid < K_SEL) { rsum[tid] = my_reg; csum[tid] = my_cls; osum[tid] = my_corr; fsum[tid] = my_first; }
        __syncthreads();
        if (tid == 0) {
            float R = 0.f, C = 0.f, O = 0.f; int F = 0;
            for (int i = 0; i < K_SEL; ++i) { R += rsum[i]; C += csum[i]; O += osum[i]; F += fsum[i]; }
            if (sel_cnt > 0) {
                atomicAdd(&facc[0], R);
                atomicAdd(&facc[1], C);
                atomicAdd(&facc[3], O);
                atomicAdd(&uacc[0], (unsigned)sel_cnt);
                atomicAdd(&uacc[1], (unsigned)F);
            }
        }
    } else {
        // -------------------- dense obj softplus base sum --------------------
        const int rb = bid - NBLK_SEL;
        const float* arrs[3] = { obj0, obj1, obj2 };
        const int    lens[3] = { 524288, 131072, 32768 };
        float s = 0.f;
        for (int a = 0; a < 3; ++a) {
            const float* p = arrs[a]; int n = lens[a];
            for (int i = rb * 256 + tid; i < n; i += NBLK_RED * 256)
                s += softplus_f(p[i]);
        }
        __shared__ float red[256];
        red[tid] = s; __syncthreads();
        for (int st = 128; st > 0; st >>= 1) {
            if (tid < st) red[tid] += red[tid + st];
            __syncthreads();
        }
        if (tid == 0) atomicAdd(&facc[2], red[0]);
    }
}

__global__ void s25d_finalize(const float* facc, const unsigned* uacc, float* out) {
    float reg_s = facc[0];
    float cls_s = facc[1];
    float obj_s = facc[2] + facc[3];
    float pos = (float)uacc[0];
    float pos_now = (float)uacc[1];
    float neg = TOTAL_PIX - pos_now;
    float pos_eps = fmaxf(pos, 1.0f);
    float total = reg_s / pos_eps + obj_s / (pos_eps + fmaxf(neg, 1.0f)) + cls_s / pos_eps;
    out[0] = isfinite(total) ? total : 0.0f;
}

extern "C" void kernel_launch(void* const* d_in, const int* in_sizes, int n_in,
                              void* d_out, int out_size, void* d_ws, size_t ws_size,
                              hipStream_t stream) {
    const float* reg0 = (const float*)d_in[0];
    const float* obj0 = (const float*)d_in[1];
    const float* cls0 = (const float*)d_in[2];
    const float* reg1 = (const float*)d_in[3];
    const float* obj1 = (const float*)d_in[4];
    const float* cls1 = (const float*)d_in[5];
    const float* reg2 = (const float*)d_in[6];
    const float* obj2 = (const float*)d_in[7];
    const float* cls2 = (const float*)d_in[8];
    const float* gt   = (const float*)d_in[9];

    // ws layout: [0,16)   float facc[4]
    //            [16,24)  uint  uacc[2]
    //            [64, 64+21504*4) flag bitmask (level0:16384w, level1:4096w, level2:1024w)
    float*    facc  = (float*)d_ws;
    unsigned* uacc  = (unsigned*)((char*)d_ws + 16);
    unsigned* flags = (unsigned*)((char*)d_ws + 64);
    size_t clear_bytes = 64 + 21504 * 4;
    hipMemsetAsync(d_ws, 0, clear_bytes, stream);

    s25d_mega<<<dim3(NBLK_SEL + NBLK_RED), dim3(256), 0, stream>>>(
        reg0, obj0, cls0, reg1, obj1, cls1, reg2, obj2, cls2, gt, facc, uacc, flags);
    s25d_finalize<<<1, 1, 0, stream>>>(facc, uacc, (float*)d_out);
}

// Round 2
// 147.437 us; speedup vs baseline: 1.1167x; 1.1167x over previous
//
#include <hip/hip_runtime.h>
#include <math.h>

// ---------------------------------------------------------------------------
// Strict2_5DLoss — 3-level triangle detection loss, forward only.
//
// R1 -> R2 change: serial 64-iteration top-K selection (500+ barriers on the
// critical-path block) replaced by exact 64-bit radix select on
// key = (dist_bits << 32) | idx  (positive float bits are monotonic; keys are
// unique so lexicographic min-K == lax.top_k semantics incl. tie-break).
// Typically converges in 2 passes (~4 barriers each). Finalize fused via
// device-scope done counter.
// ---------------------------------------------------------------------------

#define K_SEL 64
#define CAP   4096          // LDS candidate capacity (bbox cells are ~<=2.8K)
#define NBLK_SEL 768        // 3 levels * 8 batch * 32 gt
#define NBLK_RED 256
#define NBLK_TOT (NBLK_SEL + NBLK_RED)
#define TOTAL_PIX 688128.0f // 8*(65536+16384+4096)

typedef unsigned long long u64;

__device__ __forceinline__ float softplus_f(float x) {
    return fmaxf(x, 0.0f) + log1pf(expf(-fabsf(x)));
}

__device__ __forceinline__ float seg_dist(float px, float py,
                                          float x1, float y1, float x2, float y2) {
    float vx = x2 - x1, vy = y2 - y1;
    float wx = px - x1, wy = py - y1;
    float t = (wx * vx + wy * vy) / (vx * vx + vy * vy + 1e-9f);
    t = fminf(fmaxf(t, 0.0f), 1.0f);
    float dx = px - (x1 + t * vx), dy = py - (y1 + t * vy);
    return sqrtf(dx * dx + dy * dy + 1e-12f);
}

__device__ __forceinline__ bool tri_mask_dist(float px, float py,
    float Ax, float Ay, float Bx, float By, float Cx, float Cy, float* dout) {
    float d1 = (px - Bx) * (Ay - By) - (Ax - Bx) * (py - By);
    float d2 = (px - Cx) * (By - Cy) - (Bx - Cx) * (py - Cy);
    float d3 = (px - Ax) * (Cy - Ay) - (Cx - Ax) * (py - Ay);
    bool has_neg = (d1 < 0.f) || (d2 < 0.f) || (d3 < 0.f);
    bool has_pos = (d1 > 0.f) || (d2 > 0.f) || (d3 > 0.f);
    bool inside = !(has_neg && has_pos);
    float dist = fminf(seg_dist(px, py, Ax, Ay, Bx, By),
                 fminf(seg_dist(px, py, Bx, By, Cx, Cy),
                       seg_dist(px, py, Cx, Cy, Ax, Ay)));
    *dout = dist;
    return inside || (dist <= 3.0f);
}

// facc: [0]=reg_s [1]=cls_s [2]=obj_base [3]=obj_corr ; uacc: [0]=pos [1]=pos_now
__global__ __launch_bounds__(256)
void s25d_mega(const float* __restrict__ reg0, const float* __restrict__ obj0, const float* __restrict__ cls0,
               const float* __restrict__ reg1, const float* __restrict__ obj1, const float* __restrict__ cls1,
               const float* __restrict__ reg2, const float* __restrict__ obj2, const float* __restrict__ cls2,
               const float* __restrict__ gt,
               float* facc, unsigned* uacc, unsigned* done, unsigned* flags,
               float* out) {
    const int bid = blockIdx.x;
    const int tid = threadIdx.x;
    const int lane = tid & 63;
    const int wv = tid >> 6;

    if (bid < NBLK_SEL) {
        // -------------------- per-(level, b, g) selection block --------------------
        const int level = bid >> 8;
        const int pair  = bid & 255;
        const int b = pair >> 5, g = pair & 31;

        const float* regp; const float* objp; const float* clsp;
        int Ws, log2Ws, flagBase; float stride;
        if (level == 0)      { regp = reg0; objp = obj0; clsp = cls0; Ws = 256; log2Ws = 8; stride =  8.f; flagBase = 0; }
        else if (level == 1) { regp = reg1; objp = obj1; clsp = cls1; Ws = 128; log2Ws = 7; stride = 16.f; flagBase = 16384; }
        else                 { regp = reg2; objp = obj2; clsp = cls2; Ws =  64; log2Ws = 6; stride = 32.f; flagBase = 20480; }
        const int HW = Ws * Ws;

        const float* tri = gt + (size_t)((b * 32 + g) * 3) * 2;
        const float Ax = tri[0], Ay = tri[1], Bx = tri[2], By = tri[3], Cx = tri[4], Cy = tri[5];

        __shared__ unsigned skey_hi[CAP];
        __shared__ unsigned skey_lo[CAP];
        __shared__ int scnt;
        __shared__ int hist[256];
        __shared__ int wtot[4];
        __shared__ int s_d, s_below, s_cnt;
        if (tid == 0) scnt = 0;
        __syncthreads();

        // conservative bbox (+ETA, plus one-cell slack each side)
        float minx = fminf(Ax, fminf(Bx, Cx)) - 3.0f;
        float maxx = fmaxf(Ax, fmaxf(Bx, Cx)) + 3.0f;
        float miny = fminf(Ay, fminf(By, Cy)) - 3.0f;
        float maxy = fmaxf(Ay, fmaxf(By, Cy)) + 3.0f;
        int ix_lo = max(0,      (int)floorf(minx / stride - 0.5f));
        int ix_hi = min(Ws - 1, (int)ceilf (maxx / stride - 0.5f));
        int iy_lo = max(0,      (int)floorf(miny / stride - 0.5f));
        int iy_hi = min(Ws - 1, (int)ceilf (maxy / stride - 0.5f));
        int nx = ix_hi - ix_lo + 1, ny = iy_hi - iy_lo + 1;
        int ncells = (nx > 0 && ny > 0) ? nx * ny : 0;

        // ---- candidate collection (wave-aggregated LDS push) ----
        for (int base = 0; base < ncells; base += 256) {
            int c = base + tid;
            bool pred = false; unsigned dbits = 0; int idx = 0;
            if (c < ncells) {
                int ix = ix_lo + (c % nx);
                int iy = iy_lo + (c / nx);
                float px = (ix + 0.5f) * stride, py = (iy + 0.5f) * stride;
                float d;
                if (tri_mask_dist(px, py, Ax, Ay, Bx, By, Cx, Cy, &d)) {
                    pred = true;
                    dbits = __float_as_uint(d);      // d > 0 -> monotonic bits
                    idx = (iy << log2Ws) | ix;
                }
            }
            u64 m = __ballot(pred);
            if (m) {
                int rank = __popcll(m & ((1ull << lane) - 1));
                int total = __popcll(m);
                int fl = __ffsll((unsigned long long)m) - 1;
                int bs = 0;
                if (lane == fl) bs = atomicAdd(&scnt, total);
                bs = __shfl(bs, fl, 64);
                if (pred) {
                    int slot = bs + rank;
                    if (slot < CAP) { skey_hi[slot] = dbits; skey_lo[slot] = (unsigned)idx; }
                }
            }
        }
        __syncthreads();
        const int  cnt = scnt;
        const bool ovf = (cnt > CAP);
        const int  sel_cnt = min(cnt, K_SEL);

        // ---- exact 64-bit radix select of the K-th smallest key ----
        u64 threshold = ~0ull;           // cnt<=K: everything selected
        if (cnt > K_SEL) {
            u64 prefix = 0;
            int need = K_SEL;
            const int lim = ovf ? ncells : cnt;
            for (int shift = 56; shift >= 0; shift -= 8) {
                hist[tid] = 0;
                __syncthreads();
                for (int base = 0; base < lim; base += 256) {
                    int c = base + tid;
                    if (c < lim) {
                        bool has = false; u64 key = 0;
                        if (!ovf) {
                            key = ((u64)skey_hi[c] << 32) | skey_lo[c];
                            has = true;
                        } else {
                            int ix = ix_lo + (c % nx);
                            int iy = iy_lo + (c / nx);
                            float px = (ix + 0.5f) * stride, py = (iy + 0.5f) * stride;
                            float d;
                            if (tri_mask_dist(px, py, Ax, Ay, Bx, By, Cx, Cy, &d)) {
                                key = ((u64)__float_as_uint(d) << 32) | (unsigned)((iy << log2Ws) | ix);
                                has = true;
                            }
                        }
                        if (has && (shift == 56 || (key >> (shift + 8)) == prefix))
                            atomicAdd(&hist[(int)((key >> shift) & 255)], 1);
                    }
                }
                __syncthreads();
                // 256-bin inclusive scan: shfl within wave, 4 wave totals via LDS
                int v = hist[tid];
                int x = v;
#pragma unroll
                for (int dlt = 1; dlt < 64; dlt <<= 1) {
                    int y = __shfl_up(x, dlt, 64);
                    if (lane >= dlt) x += y;
                }
                if (lane == 63) wtot[wv] = x;
                __syncthreads();
                int pre = 0;
                for (int i = 0; i < wv; ++i) pre += wtot[i];
                int cum = x + pre;
                int below = cum - v;
                if (cum >= need && below < need) { s_d = tid; s_below = below; s_cnt = v; }
                __syncthreads();
                int d = s_d, bl = s_below, bc = s_cnt;
                prefix = (prefix << 8) | (unsigned)d;
                if (bl + bc == need) {   // pivot bin count == remaining need -> exact
                    threshold = (prefix << shift) | (shift ? ((1ull << shift) - 1) : 0ull);
                    break;
                }
                need -= bl;
                // keys are unique -> by shift==0 hist counts are 1 and the
                // condition above must fire; no fallthrough possible.
            }
        }
        __syncthreads();

        // -------------------- contribution pass over selected set --------------------
        float my_reg = 0.f, my_cls = 0.f, my_corr = 0.f; float my_first = 0.f;
        {
            const float inv = 1.0f / stride;
            const int lim = ovf ? ncells : min(cnt, CAP);
            for (int base = 0; base < lim; base += 256) {
                int c = base + tid;
                if (c >= lim) continue;
                bool has = false; u64 key = 0; int hw = 0;
                if (!ovf) {
                    unsigned lo = skey_lo[c];
                    key = ((u64)skey_hi[c] << 32) | lo;
                    hw = (int)lo; has = true;
                } else {
                    int ix = ix_lo + (c % nx);
                    int iy = iy_lo + (c / nx);
                    float px = (ix + 0.5f) * stride, py = (iy + 0.5f) * stride;
                    float d;
                    if (tri_mask_dist(px, py, Ax, Ay, Bx, By, Cx, Cy, &d)) {
                        hw = (iy << log2Ws) | ix;
                        key = ((u64)__float_as_uint(d) << 32) | (unsigned)hw;
                        has = true;
                    }
                }
                if (!has || key > threshold) continue;

                int ix = hw & (Ws - 1), iy = hw >> log2Ws;
                float ax = (ix + 0.5f) * stride, ay = (iy + 0.5f) * stride;
                int pix = b * HW + hw;

                // distinct-pixel dedup (per level, per batch) for obj_t / pos_now
                int word = flagBase + (pix >> 5);
                unsigned bit = 1u << (pix & 31);
                unsigned old = atomicOr(&flags[word], bit);
                if (!(old & bit)) {
                    my_first += 1.f;
                    float xo = objp[pix];
                    my_corr += 1.2f * softplus_f(-xo) - softplus_f(xo);
                }
                my_cls += softplus_f(-clsp[pix]);

                float p[6];
#pragma unroll
                for (int ch = 0; ch < 6; ++ch) {
                    float vv = regp[(size_t)(b * 6 + ch) * HW + hw];
                    p[ch] = fminf(fmaxf(vv, -64.f), 64.f);
                }
                float g0x = (Ax - ax) * inv, g0y = (Ay - ay) * inv;
                float g1x = (Bx - ax) * inv, g1y = (By - ay) * inv;
                float g2x = (Cx - ax) * inv, g2y = (Cy - ay) * inv;
                float p0 = (p[0] - g0x) * (p[0] - g0x) + (p[1] - g0y) * (p[1] - g0y);
                float d00 = sqrtf((p[2] - g1x) * (p[2] - g1x) + (p[3] - g1y) * (p[3] - g1y));
                float d01 = sqrtf((p[2] - g2x) * (p[2] - g2x) + (p[3] - g2y) * (p[3] - g2y));
                float d10 = sqrtf((p[4] - g1x) * (p[4] - g1x) + (p[5] - g1y) * (p[5] - g1y));
                float d11 = sqrtf((p[4] - g2x) * (p[4] - g2x) + (p[5] - g2y) * (p[5] - g2y));
                float cd = fminf(d00, d01) + fminf(d10, d11) + fminf(d00, d10) + fminf(d01, d11);
                my_reg += p0 + cd;
            }
        }

        // block reduce (shfl within wave, LDS across 4 waves)
        __shared__ float r4[4], c4[4], o4[4], f4[4];
#pragma unroll
        for (int dlt = 32; dlt > 0; dlt >>= 1) {
            my_reg   += __shfl_down(my_reg, dlt, 64);
            my_cls   += __shfl_down(my_cls, dlt, 64);
            my_corr  += __shfl_down(my_corr, dlt, 64);
            my_first += __shfl_down(my_first, dlt, 64);
        }
        if (lane == 0) { r4[wv] = my_reg; c4[wv] = my_cls; o4[wv] = my_corr; f4[wv] = my_first; }
        __syncthreads();
        if (tid == 0 && sel_cnt > 0) {
            float R = r4[0] + r4[1] + r4[2] + r4[3];
            float C = c4[0] + c4[1] + c4[2] + c4[3];
            float O = o4[0] + o4[1] + o4[2] + o4[3];
            float F = f4[0] + f4[1] + f4[2] + f4[3];
            atomicAdd(&facc[0], R);
            atomicAdd(&facc[1], C);
            atomicAdd(&facc[3], O);
            atomicAdd(&uacc[0], (unsigned)sel_cnt);
            atomicAdd(&uacc[1], (unsigned)(F + 0.5f));
        }
    } else {
        // -------------------- dense obj softplus base sum --------------------
        const int rb = bid - NBLK_SEL;
        const float* arrs[3] = { obj0, obj1, obj2 };
        const int    lens[3] = { 524288, 131072, 32768 };
        float s = 0.f;
        for (int a = 0; a < 3; ++a) {
            const float* p = arrs[a]; int n = lens[a];
            for (int i = rb * 256 + tid; i < n; i += NBLK_RED * 256)
                s += softplus_f(p[i]);
        }
        __shared__ float red4[4];
#pragma unroll
        for (int dlt = 32; dlt > 0; dlt >>= 1) s += __shfl_down(s, dlt, 64);
        if (lane == 0) red4[wv] = s;
        __syncthreads();
        if (tid == 0) atomicAdd(&facc[2], red4[0] + red4[1] + red4[2] + red4[3]);
    }

    // -------------------- fused finalize: last block computes total --------------------
    if (tid == 0) {
        __threadfence();
        unsigned prev = atomicAdd(done, 1u);
        if (prev == NBLK_TOT - 1) {
            float reg_s = atomicAdd(&facc[0], 0.0f);
            float cls_s = atomicAdd(&facc[1], 0.0f);
            float obj_s = atomicAdd(&facc[2], 0.0f) + atomicAdd(&facc[3], 0.0f);
            float pos = (float)atomicAdd(&uacc[0], 0u);
            float pos_now = (float)atomicAdd(&uacc[1], 0u);
            float neg = TOTAL_PIX - pos_now;
            float pos_eps = fmaxf(pos, 1.0f);
            float total = reg_s / pos_eps + obj_s / (pos_eps + fmaxf(neg, 1.0f)) + cls_s / pos_eps;
            out[0] = isfinite(total) ? total : 0.0f;
        }
    }
}

extern "C" void kernel_launch(void* const* d_in, const int* in_sizes, int n_in,
                              void* d_out, int out_size, void* d_ws, size_t ws_size,
                              hipStream_t stream) {
    const float* reg0 = (const float*)d_in[0];
    const float* obj0 = (const float*)d_in[1];
    const float* cls0 = (const float*)d_in[2];
    const float* reg1 = (const float*)d_in[3];
    const float* obj1 = (const float*)d_in[4];
    const float* cls1 = (const float*)d_in[5];
    const float* reg2 = (const float*)d_in[6];
    const float* obj2 = (const float*)d_in[7];
    const float* cls2 = (const float*)d_in[8];
    const float* gt   = (const float*)d_in[9];

    // ws layout: [0,16) float facc[4] | [16,24) uint uacc[2] | [24,28) uint done
    //            [64, 64+21504*4) flag bitmask (lvl0:16384w, lvl1:4096w, lvl2:1024w)
    float*    facc  = (float*)d_ws;
    unsigned* uacc  = (unsigned*)((char*)d_ws + 16);
    unsigned* done  = (unsigned*)((char*)d_ws + 24);
    unsigned* flags = (unsigned*)((char*)d_ws + 64);
    size_t clear_bytes = 64 + 21504 * 4;
    hipMemsetAsync(d_ws, 0, clear_bytes, stream);

    s25d_mega<<<dim3(NBLK_TOT), dim3(256), 0, stream>>>(
        reg0, obj0, cls0, reg1, obj1, cls1, reg2, obj2, cls2, gt,
        facc, uacc, done, flags, (float*)d_out);
}